// Round 1
// baseline (131.218 us; speedup 1.0000x reference)
//
#include <hip/hip_runtime.h>

// FSUMatMul one-cycle. Exact identity: with in_f = scale_carry = 2048 and
// DEPTH=12 (bound 4095 > 2048), the emitted bit is
//   out[b,o] = (sum_k XNOR(x[b,k], path[o,k]) == in_f)
//            = (x row b bit-identical to path row o).
// So: pack x bits and path bits into 32x u64 per row, then compare rows.
// Traffic floor = read x (33.5MB) + read w (33.5MB) + write out (67MB) = 134MB.

#define BATCH 4096
#define INF   2048
#define OUTF  4096
#define WORDS 32            // INF / 64 bits per u64
#define NX_CHUNKS ((BATCH * INF) / 256)   // 32768 x-chunks of 256 floats
#define NW_CHUNKS ((OUTF  * INF) / 256)   // 32768 w-chunks

// One wave (64 lanes) packs one 256-float chunk into 4 u64 words via ballot.
// Chunk ids [0, NX_CHUNKS) -> x, [NX_CHUNKS, NX+NW) -> w (path bits).
// xp layout: row-major xp[b*32 + w].  pp layout: WORD-MAJOR pp[w*OUTF + o]
// so the compare kernel's word-0 loads are coalesced across o.
__global__ __launch_bounds__(256) void pack_kernel(
    const float* __restrict__ x, const float* __restrict__ w,
    const float* __restrict__ rng,
    unsigned long long* __restrict__ xp, unsigned long long* __restrict__ pp)
{
    const int tid  = threadIdx.x;
    const int wav  = tid >> 6;
    const int lane = tid & 63;
    const int chunk = blockIdx.x * 4 + wav;          // wave-uniform
    const float r = rng[0];

    if (chunk < NX_CHUNKS) {
        const float4 v = *reinterpret_cast<const float4*>(
            x + (size_t)chunk * 256 + lane * 4);
        unsigned long long b0 = __ballot(v.x != 0.0f);
        unsigned long long b1 = __ballot(v.y != 0.0f);
        unsigned long long b2 = __ballot(v.z != 0.0f);
        unsigned long long b3 = __ballot(v.w != 0.0f);
        if (lane == 0) {
            size_t base = (size_t)chunk * 4;
            xp[base + 0] = b0; xp[base + 1] = b1;
            xp[base + 2] = b2; xp[base + 3] = b3;
        }
    } else {
        const int c2 = chunk - NX_CHUNKS;
        const float4 v = *reinterpret_cast<const float4*>(
            w + (size_t)c2 * 256 + lane * 4);
        // BinGen/BSGen: source = round((w+1)*0.5 * 2^WIDTH); path = source > rng.
        // Matches jnp.round: (w+1) single-rounded, *0.5 and *256 exact
        // (power-of-2), rintf = round-half-to-even.
        float s0 = rintf((v.x + 1.0f) * 0.5f * 256.0f);
        float s1 = rintf((v.y + 1.0f) * 0.5f * 256.0f);
        float s2 = rintf((v.z + 1.0f) * 0.5f * 256.0f);
        float s3 = rintf((v.w + 1.0f) * 0.5f * 256.0f);
        unsigned long long b0 = __ballot(s0 > r);
        unsigned long long b1 = __ballot(s1 > r);
        unsigned long long b2 = __ballot(s2 > r);
        unsigned long long b3 = __ballot(s3 > r);
        const int o  = c2 >> 3;   // row of w (out feature), 8 chunks per row
        const int rr = c2 & 7;    // chunk within row -> words rr*4 .. rr*4+3
        if (lane == 0) {
            pp[(size_t)(rr * 4 + 0) * OUTF + o] = b0;
            pp[(size_t)(rr * 4 + 1) * OUTF + o] = b1;
            pp[(size_t)(rr * 4 + 2) * OUTF + o] = b2;
            pp[(size_t)(rr * 4 + 3) * OUTF + o] = b3;
        }
    }
}

// out[b, o0..o0+3] per thread; 16 b-rows per block. Fast path compares
// word 0 only; __any-guarded slow path (vanishingly rare) verifies all 32
// words so the result is exact for ANY input.
__global__ __launch_bounds__(256) void cmp_kernel(
    const unsigned long long* __restrict__ xp,
    const unsigned long long* __restrict__ pp,
    float* __restrict__ out)
{
    const int tid = threadIdx.x;
    const int o0  = (blockIdx.x * 256 + tid) * 4;
    const int b0  = blockIdx.y * 16;

    // word-0 of 4 consecutive path rows: coalesced (32B/thread contiguous)
    const unsigned long long p0 = pp[o0 + 0];
    const unsigned long long p1 = pp[o0 + 1];
    const unsigned long long p2 = pp[o0 + 2];
    const unsigned long long p3 = pp[o0 + 3];

    for (int i = 0; i < 16; ++i) {
        const int b = b0 + i;
        const unsigned long long xw = xp[(size_t)b * WORDS];  // uniform -> s_load
        bool e0 = (p0 == xw);
        bool e1 = (p1 == xw);
        bool e2 = (p2 == xw);
        bool e3 = (p3 == xw);
        if (__any(e0 | e1 | e2 | e3)) {         // ~never taken, wave-uniform skip
            for (int wd = 1; wd < WORDS; ++wd) {
                const unsigned long long xx = xp[(size_t)b * WORDS + wd];
                const unsigned long long* prow = pp + (size_t)wd * OUTF + o0;
                e0 = e0 && (prow[0] == xx);
                e1 = e1 && (prow[1] == xx);
                e2 = e2 && (prow[2] == xx);
                e3 = e3 && (prow[3] == xx);
            }
        }
        float4 res = make_float4(e0 ? 1.0f : 0.0f, e1 ? 1.0f : 0.0f,
                                 e2 ? 1.0f : 0.0f, e3 ? 1.0f : 0.0f);
        *reinterpret_cast<float4*>(out + (size_t)b * OUTF + o0) = res;
    }
}

extern "C" void kernel_launch(void* const* d_in, const int* in_sizes, int n_in,
                              void* d_out, int out_size, void* d_ws, size_t ws_size,
                              hipStream_t stream) {
    const float* x   = (const float*)d_in[0];   // (4096, 2048) {0,1}
    const float* w   = (const float*)d_in[1];   // (4096, 2048) [-1,1]
    const float* rng = (const float*)d_in[2];   // scalar 128.0
    float* out = (float*)d_out;                 // (4096, 4096)

    unsigned long long* xp = (unsigned long long*)d_ws;      // 4096*32 u64 = 1MB
    unsigned long long* pp = xp + (size_t)BATCH * WORDS;     // 32*4096 u64 = 1MB

    // 65536 chunks total, 4 waves (chunks) per 256-thread block
    pack_kernel<<<dim3((NX_CHUNKS + NW_CHUNKS) / 4), dim3(256), 0, stream>>>(
        x, w, rng, xp, pp);

    // grid: 4 o-tiles (1024 cols each) x 256 b-tiles (16 rows each)
    cmp_kernel<<<dim3(OUTF / 1024, BATCH / 16), dim3(256), 0, stream>>>(
        xp, pp, out);
}

// Round 2
// 108.098 us; speedup vs baseline: 1.2139x; 1.2139x over previous
//
#include <hip/hip_runtime.h>

// FSUMatMul one-cycle. Exact identity: with in_f = scale_carry = 2048 and
// DEPTH=12 (bound 4095 > 2048), the emitted bit is
//   out[b,o] = (sum_k XNOR(x[b,k], path[o,k]) == in_f)
//            = (x row b bit-identical to path row o, all 2048 bits).
//
// Fast path: compare only the first 64 bits (word 0) of each row, packed by
// a tiny kernel (2 MB of reads). If word 0 matches (prob ~2^-64 per pair),
// a slow path verifies the remaining 1984 bits directly from the pristine
// x/w in global memory — exact for ANY input, ~never executed for this one.
//
// Controllable traffic: pack reads 2 MB; cmp writes the mandatory 67 MB out.

#define BATCH 4096
#define INF   2048
#define OUTF  4096

// One wave packs the first 64 columns of one row (x or w->path) via ballot.
// ids [0, BATCH) -> x rows, [BATCH, BATCH+OUTF) -> w rows.
__global__ __launch_bounds__(256) void pack0_kernel(
    const float* __restrict__ x, const float* __restrict__ w,
    const float* __restrict__ rng,
    unsigned long long* __restrict__ xp0, unsigned long long* __restrict__ pp0)
{
    const int lane = threadIdx.x & 63;
    const int wav  = threadIdx.x >> 6;
    const int id   = blockIdx.x * 4 + wav;          // wave-uniform

    if (id < BATCH) {
        const float v = x[(size_t)id * INF + lane]; // 256B coalesced per wave
        const unsigned long long b = __ballot(v != 0.0f);
        if (lane == 0) xp0[id] = b;
    } else {
        const int o = id - BATCH;
        const float v = w[(size_t)o * INF + lane];
        // BinGen/BSGen: source = round((w+1)*0.5*2^WIDTH); path = source > rng.
        // rintf = round-half-even matches jnp.round; *0.5 and *256 exact.
        const float s = rintf((v + 1.0f) * 0.5f * 256.0f);
        const unsigned long long b = __ballot(s > rng[0]);
        if (lane == 0) pp0[o] = b;
    }
}

// out[b, o0..o0+3] per thread; 16 b-rows per block. Fast path compares
// word 0 only; per-thread rare path re-verifies bits 64..2047 straight from
// the raw inputs so the result is exact for ANY input.
__global__ __launch_bounds__(256) void cmp_kernel(
    const unsigned long long* __restrict__ xp0,
    const unsigned long long* __restrict__ pp0,
    const float* __restrict__ x, const float* __restrict__ w,
    const float* __restrict__ rng,
    float* __restrict__ out)
{
    const int tid = threadIdx.x;
    const int o0  = (blockIdx.x * 256 + tid) * 4;
    const int b0  = blockIdx.y * 16;

    // word-0 of 4 consecutive path rows: 32B/thread contiguous -> coalesced
    const unsigned long long p0 = pp0[o0 + 0];
    const unsigned long long p1 = pp0[o0 + 1];
    const unsigned long long p2 = pp0[o0 + 2];
    const unsigned long long p3 = pp0[o0 + 3];

    for (int i = 0; i < 16; ++i) {
        const int b = b0 + i;
        const unsigned long long xw = xp0[b];       // block-uniform
        bool eq[4];
        eq[0] = (p0 == xw);
        eq[1] = (p1 == xw);
        eq[2] = (p2 == xw);
        eq[3] = (p3 == xw);
        if (eq[0] | eq[1] | eq[2] | eq[3]) {        // ~never taken
            const float r = rng[0];
            for (int j = 0; j < 4; ++j) {
                if (!eq[j]) continue;
                const int o = o0 + j;
                bool all = true;
                for (int k = 64; k < INF; ++k) {
                    const bool xb = x[(size_t)b * INF + k] != 0.0f;
                    const bool pb =
                        rintf((w[(size_t)o * INF + k] + 1.0f) * 0.5f * 256.0f) > r;
                    all = all && (xb == pb);
                }
                eq[j] = all;
            }
        }
        float4 res = make_float4(eq[0] ? 1.0f : 0.0f, eq[1] ? 1.0f : 0.0f,
                                 eq[2] ? 1.0f : 0.0f, eq[3] ? 1.0f : 0.0f);
        *reinterpret_cast<float4*>(out + (size_t)b * OUTF + o0) = res;
    }
}

extern "C" void kernel_launch(void* const* d_in, const int* in_sizes, int n_in,
                              void* d_out, int out_size, void* d_ws, size_t ws_size,
                              hipStream_t stream) {
    const float* x   = (const float*)d_in[0];   // (4096, 2048) {0,1}
    const float* w   = (const float*)d_in[1];   // (4096, 2048) [-1,1]
    const float* rng = (const float*)d_in[2];   // scalar 128.0
    float* out = (float*)d_out;                 // (4096, 4096)

    unsigned long long* xp0 = (unsigned long long*)d_ws;   // 4096 u64 = 32KB
    unsigned long long* pp0 = xp0 + BATCH;                 // 4096 u64 = 32KB

    // 8192 word-0 packs, 4 waves per 256-thread block -> 2048 blocks
    pack0_kernel<<<dim3((BATCH + OUTF) / 4), dim3(256), 0, stream>>>(
        x, w, rng, xp0, pp0);

    // grid: 4 o-tiles (1024 cols each) x 256 b-tiles (16 rows each)
    cmp_kernel<<<dim3(OUTF / 1024, BATCH / 16), dim3(256), 0, stream>>>(
        xp0, pp0, x, w, rng, out);
}